// Round 2
// baseline (145.762 us; speedup 1.0000x reference)
//
#include <hip/hip_runtime.h>
#include <hip/hip_bf16.h>

#define Bn   32768
#define Tn   200
#define In   6
#define Hn   6
#define FFn  128
#define OUTn 12
#define KP   1600   // padded K = Tn * 8 (6 h-values + 2 zero slots per step)

typedef __attribute__((ext_vector_type(4))) float          f32x4;
typedef __attribute__((ext_vector_type(8))) short          bf16x8;
typedef __attribute__((ext_vector_type(4))) unsigned short u16x4;
typedef __attribute__((ext_vector_type(8))) unsigned short u16x8;

__device__ __forceinline__ float sigf(float v) {
    // 1 / (1 + exp(-v)); stable at +/-inf (rcp(inf)=0)
    return __builtin_amdgcn_rcpf(1.f + __builtin_amdgcn_exp2f(-1.442695041f * v));
}
__device__ __forceinline__ float tanhf_(float v) {
    // 1 - 2/(1 + exp(2v)); stable at +/-inf
    return fmaf(-2.f, __builtin_amdgcn_rcpf(1.f + __builtin_amdgcn_exp2f(2.885390082f * v)), 1.f);
}
__device__ __forceinline__ float swap1(float v) {
    // exchange with lane^1 (pairs are even-aligned, never cross wave)
    return __int_as_float(__builtin_amdgcn_mov_dpp(__float_as_int(v), 0xB1, 0xF, 0xF, true));
}
__device__ __forceinline__ unsigned short f2bf(float v) {
    // round-to-nearest-even f32 -> bf16 (values are tame, no NaN/Inf handling needed)
    unsigned u = __float_as_uint(v);
    unsigned r = u + 0x7FFFu + ((u >> 16) & 1u);
    return (unsigned short)(r >> 16);
}

// Build W1' [FFn][KP] bf16 from W1 [FFn][Tn*Hn] fp32 with the padded-slot mapping:
// slot p: 0,1,2 -> h 0,1,2 ; 4,5,6 -> h 3,4,5 ; 3,7 -> zero
__global__ void prep_kernel(const float* __restrict__ W1, unsigned short* __restrict__ W1p) {
    int idx = blockIdx.x * 256 + threadIdx.x;
    if (idx >= FFn * KP) return;
    int ff = idx / KP, kp = idx - ff * KP;
    int t = kp >> 3, p = kp & 7;
    float v = 0.f;
    if (p != 3 && p != 7) {
        int h = (p < 3) ? p : (p - 1);
        v = W1[ff * (Tn * Hn) + t * Hn + h];
    }
    W1p[idx] = f2bf(v);
}

__global__ __launch_bounds__(256, 1)
void fused_kernel(const float* __restrict__ x,
                  const float* __restrict__ W_ih, const float* __restrict__ W_hh,
                  const float* __restrict__ b_ih, const float* __restrict__ b_hh,
                  const unsigned short* __restrict__ W1p,
                  const float* __restrict__ b1,
                  const float* __restrict__ W2, const float* __restrict__ b2,
                  float* __restrict__ out)
{
    // LDS: double-buffered h tile (4 steps x 128 samples x 8 padded bf16) = 16 KB
    //      + bf16 hid [128][136] (34 KB) + fp32 W2 (6 KB)  => 56 KB total
    __shared__ unsigned short htile[2][4][128][8];
    __shared__ unsigned short hidS[128][136];
    __shared__ float          W2s[OUTn * FFn];

    const int tid  = threadIdx.x;
    const int sloc = tid >> 1;      // local sample 0..127
    const int role = tid & 1;       // 0: hidden units 0..2, 1: units 3..5
    const int b0   = blockIdx.x * 128;
    const int wv   = tid >> 6;      // wave 0..3
    const int l    = tid & 63;
    const int lr   = l & 15;        // MFMA row/col lane
    const int lg   = l >> 4;        // MFMA k-group

    // ---- per-lane gate weights in VGPRs (12 rows x 6) ----
    // j = gt*3 + m ; global gate row = gt*6 + role*3 + m  (gate order i,f,g,o)
    // Whh reordered: cols 0..2 = own units, 3..5 = partner units
    float Wih[12][6], Whh[12][6], bias[12];
    #pragma unroll
    for (int gt = 0; gt < 4; ++gt) {
        #pragma unroll
        for (int m = 0; m < 3; ++m) {
            const int j = gt * 3 + m;
            const int row = gt * 6 + role * 3 + m;
            #pragma unroll
            for (int k = 0; k < 6; ++k) Wih[j][k] = W_ih[row * 6 + k];
            #pragma unroll
            for (int k = 0; k < 3; ++k) Whh[j][k]     = W_hh[row * 6 + role * 3 + k];
            #pragma unroll
            for (int k = 0; k < 3; ++k) Whh[j][3 + k] = W_hh[row * 6 + (1 - role) * 3 + k];
            bias[j] = b_ih[row] + b_hh[row];
        }
    }

    float hOwn[3] = {0.f, 0.f, 0.f}, hOth[3] = {0.f, 0.f, 0.f}, cS[3] = {0.f, 0.f, 0.f};

    f32x4 acc[8][2];
    #pragma unroll
    for (int m = 0; m < 8; ++m)
        #pragma unroll
        for (int n = 0; n < 2; ++n)
            acc[m][n] = (f32x4){0.f, 0.f, 0.f, 0.f};

    // x staging: both lanes of a pair load the full 4-step chunk (same addresses -> coalescer dedup)
    const f32x4* xb4 = (const f32x4*)(x + (size_t)(b0 + sloc) * (Tn * In));
    f32x4 bufA[6], bufB[6];
    #pragma unroll
    for (int q = 0; q < 6; ++q) bufA[q] = xb4[q];

    auto STEPS = [&](const f32x4 (&bx)[6], int tb) {
        #pragma unroll
        for (int s = 0; s < 4; ++s) {
            float xv[6];
            #pragma unroll
            for (int k = 0; k < 6; ++k) { const int fl = s * 6 + k; xv[k] = bx[fl >> 2][fl & 3]; }
            float a[12];
            #pragma unroll
            for (int j = 0; j < 12; ++j) {
                float t_ = bias[j];
                #pragma unroll
                for (int k = 0; k < 6; ++k) t_ = fmaf(Wih[j][k], xv[k], t_);
                #pragma unroll
                for (int k = 0; k < 3; ++k) t_ = fmaf(Whh[j][k], hOwn[k], t_);
                #pragma unroll
                for (int k = 0; k < 3; ++k) t_ = fmaf(Whh[j][3 + k], hOth[k], t_);
                a[j] = t_;
            }
            unsigned short hb[3];
            #pragma unroll
            for (int m = 0; m < 3; ++m) {
                const float iv = sigf(a[m]);
                const float fv = sigf(a[3 + m]);
                const float gv = tanhf_(a[6 + m]);
                const float ov = sigf(a[9 + m]);
                const float c  = fmaf(fv, cS[m], iv * gv);
                cS[m] = c;
                const float hv = ov * tanhf_(c);
                hOwn[m] = hv;
                hOth[m] = swap1(hv);   // partner's value of the same register
                hb[m]   = f2bf(hv);
            }
            u16x4 hw; hw.x = hb[0]; hw.y = hb[1]; hw.z = hb[2]; hw.w = 0;
            *((u16x4*)&htile[tb & 1][s][sloc][role * 4]) = hw;
        }
    };

    auto MFMAG = [&](int kb) {
        const unsigned short* tb_ = &htile[kb & 1][0][0][0];
        bf16x8 af[8];
        #pragma unroll
        for (int m = 0; m < 8; ++m)
            af[m] = *((const bf16x8*)&tb_[(lg * 128 + m * 16 + lr) * 8]);
        #pragma unroll
        for (int n = 0; n < 2; ++n) {
            const bf16x8 bf = *((const bf16x8*)&W1p[(size_t)(wv * 32 + n * 16 + lr) * KP + kb * 32 + lg * 8]);
            #pragma unroll
            for (int m = 0; m < 8; ++m)
                acc[m][n] = __builtin_amdgcn_mfma_f32_16x16x32_bf16(af[m], bf, acc[m][n], 0, 0, 0);
        }
    };

    for (int g2 = 0; g2 < 25; ++g2) {
        const int tA = 2 * g2, tB = 2 * g2 + 1;
        #pragma unroll
        for (int q = 0; q < 6; ++q) bufB[q] = xb4[tB * 6 + q];   // prefetch odd group
        STEPS(bufA, tA);
        __syncthreads();
        MFMAG(tA);
        const int tN = (tA + 2 < 50) ? (tA + 2) : 49;            // clamped (garbage unused at end)
        #pragma unroll
        for (int q = 0; q < 6; ++q) bufA[q] = xb4[tN * 6 + q];   // prefetch next even group
        STEPS(bufB, tB);
        __syncthreads();
        MFMAG(tB);
    }

    // ---- epilogue: hid = relu(acc + b1) -> LDS bf16; then out = hid @ W2^T + b2 (fp32 VALU) ----
    float b1v[2];
    #pragma unroll
    for (int n = 0; n < 2; ++n) b1v[n] = b1[wv * 32 + n * 16 + lr];
    #pragma unroll
    for (int m = 0; m < 8; ++m)
        #pragma unroll
        for (int n = 0; n < 2; ++n)
            #pragma unroll
            for (int r = 0; r < 4; ++r)
                hidS[m * 16 + lg * 4 + r][wv * 32 + n * 16 + lr] =
                    f2bf(fmaxf(acc[m][n][r] + b1v[n], 0.f));
    for (int q = tid; q < OUTn * FFn; q += 256) W2s[q] = W2[q];
    __syncthreads();

    const int s2 = tid >> 1;
    const int half = tid & 1;   // 6 outputs each
    float oa[6];
    #pragma unroll
    for (int jj = 0; jj < 6; ++jj) oa[jj] = b2[half * 6 + jj];
    for (int k8 = 0; k8 < 16; ++k8) {
        const u16x8 hv8 = *((const u16x8*)&hidS[s2][k8 * 8]);
        #pragma unroll
        for (int e = 0; e < 8; ++e) {
            const float hv = __uint_as_float(((unsigned)(unsigned short)hv8[e]) << 16);
            const int k = k8 * 8 + e;
            #pragma unroll
            for (int jj = 0; jj < 6; ++jj)
                oa[jj] = fmaf(hv, W2s[(half * 6 + jj) * FFn + k], oa[jj]);
        }
    }
    float* op = out + (size_t)(b0 + s2) * OUTn + half * 6;
    #pragma unroll
    for (int jj = 0; jj < 6; ++jj) op[jj] = oa[jj];
}

extern "C" void kernel_launch(void* const* d_in, const int* in_sizes, int n_in,
                              void* d_out, int out_size, void* d_ws, size_t ws_size,
                              hipStream_t stream) {
    const float* x    = (const float*)d_in[0];
    const float* W_ih = (const float*)d_in[1];
    const float* W_hh = (const float*)d_in[2];
    const float* b_ih = (const float*)d_in[3];
    const float* b_hh = (const float*)d_in[4];
    const float* W1   = (const float*)d_in[5];
    const float* b1   = (const float*)d_in[6];
    const float* W2   = (const float*)d_in[7];
    const float* b2   = (const float*)d_in[8];
    unsigned short* W1p = (unsigned short*)d_ws;   // 128*1600*2B = 400 KB
    float* out = (float*)d_out;

    prep_kernel<<<(FFn * KP + 255) / 256, 256, 0, stream>>>(W1, W1p);
    fused_kernel<<<Bn / 128, 256, 0, stream>>>(x, W_ih, W_hh, b_ih, b_hh,
                                               W1p, b1, W2, b2, out);
}

// Round 3
// 116.422 us; speedup vs baseline: 1.2520x; 1.2520x over previous
//
#include <hip/hip_runtime.h>
#include <hip/hip_bf16.h>

#define Bn   32768
#define Tn   200
#define In   6
#define Hn   6
#define FFn  128
#define OUTn 12
#define KP   1600   // padded K = Tn * 8 (6 h-values + 2 zero slots per step)

typedef __attribute__((ext_vector_type(2))) float          f32x2;
typedef __attribute__((ext_vector_type(4))) float          f32x4;
typedef __attribute__((ext_vector_type(8))) short          bf16x8;
typedef __attribute__((ext_vector_type(4))) unsigned short u16x4;
typedef __attribute__((ext_vector_type(8))) unsigned short u16x8;

#define LOG2E 1.442695041f

__device__ __forceinline__ f32x2 pkfma(f32x2 a, f32x2 b, f32x2 c) {
#if __has_builtin(__builtin_elementwise_fma)
    return __builtin_elementwise_fma(a, b, c);   // -> v_pk_fma_f32
#else
    return a * b + c;
#endif
}
__device__ __forceinline__ float rcp1p(float e) {
    // 1 / (1 + 2^e)
    return __builtin_amdgcn_rcpf(1.f + __builtin_amdgcn_exp2f(e));
}
__device__ __forceinline__ float tanh_c(float c) {
    return fmaf(-2.f, rcp1p(2.f * LOG2E * c), 1.f);
}
__device__ __forceinline__ float swap1(float v) {
    // exchange with lane^1 (pairs are even-aligned, never cross wave)
    return __int_as_float(__builtin_amdgcn_mov_dpp(__float_as_int(v), 0xB1, 0xF, 0xF, true));
}
__device__ __forceinline__ unsigned short f2bf(float v) {
    unsigned u = __float_as_uint(v);
    unsigned r = u + 0x7FFFu + ((u >> 16) & 1u);
    return (unsigned short)(r >> 16);
}

// lgkmcnt-only barrier: LDS writes visible, vmcnt loads stay in flight across it
#define BAR() do {                                          \
    asm volatile("s_waitcnt lgkmcnt(0)" ::: "memory");      \
    __builtin_amdgcn_sched_barrier(0);                      \
    __builtin_amdgcn_s_barrier();                           \
    __builtin_amdgcn_sched_barrier(0);                      \
} while (0)

// Build W1' [FFn][KP] bf16 from W1 [FFn][Tn*Hn] fp32 with the padded-slot mapping:
// slot p: 0,1,2 -> h 0,1,2 ; 4,5,6 -> h 3,4,5 ; 3,7 -> zero
__global__ void prep_kernel(const float* __restrict__ W1, unsigned short* __restrict__ W1p) {
    int idx = blockIdx.x * 256 + threadIdx.x;
    if (idx >= FFn * KP) return;
    int ff = idx / KP, kp = idx - ff * KP;
    int t = kp >> 3, p = kp & 7;
    float v = 0.f;
    if (p != 3 && p != 7) {
        int h = (p < 3) ? p : (p - 1);
        v = W1[ff * (Tn * Hn) + t * Hn + h];
    }
    W1p[idx] = f2bf(v);
}

__global__ __launch_bounds__(256, 1)
void fused_kernel(const float* __restrict__ x,
                  const float* __restrict__ W_ih, const float* __restrict__ W_hh,
                  const float* __restrict__ b_ih, const float* __restrict__ b_hh,
                  const unsigned short* __restrict__ W1p,
                  const float* __restrict__ b1,
                  const float* __restrict__ W2, const float* __restrict__ b2,
                  float* __restrict__ out)
{
    // LDS: double-buffered h tile (8 steps x 128 samples x 8 padded bf16) x2 = 32 KB
    //      + bf16 hid [128][136] (34 KB) + fp32 W2 (6 KB)  => 72 KB total
    __shared__ unsigned short htile[2][8][128][8];
    __shared__ unsigned short hidS[128][136];
    __shared__ float          W2s[OUTn * FFn];

    const int tid  = threadIdx.x;
    const int sloc = tid >> 1;      // local sample 0..127
    const int role = tid & 1;       // 0: hidden units 0..2, 1: units 3..5
    const int b0   = blockIdx.x * 128;
    const int wv   = tid >> 6;      // wave 0..3
    const int l    = tid & 63;
    const int lr   = l & 15;        // MFMA row/col lane
    const int lg   = l >> 4;        // MFMA k-group

    // ---- per-lane gate weights in VGPRs, packed in row-pairs with the
    // activation scale folded in (sig rows: -log2e ; g rows: +2*log2e) ----
    // j = gt*3 + m ; global gate row = gt*6 + role*3 + m  (gate order i,f,g,o)
    // pair p = j>>1, half = j&1. Wh cols 0..2 = own units, 3..5 = partner units.
    f32x2 Wx[6][6], Wh[6][6], bias2[6];
    #pragma unroll
    for (int gt = 0; gt < 4; ++gt) {
        #pragma unroll
        for (int m = 0; m < 3; ++m) {
            const int j = gt * 3 + m;
            const int p = j >> 1, hf = j & 1;
            const int row = gt * 6 + role * 3 + m;
            const float sc = (gt == 2) ? (2.f * LOG2E) : (-LOG2E);
            #pragma unroll
            for (int k = 0; k < 6; ++k) Wx[p][k][hf] = sc * W_ih[row * 6 + k];
            #pragma unroll
            for (int k = 0; k < 3; ++k) Wh[p][k][hf]     = sc * W_hh[row * 6 + role * 3 + k];
            #pragma unroll
            for (int k = 0; k < 3; ++k) Wh[p][3 + k][hf] = sc * W_hh[row * 6 + (1 - role) * 3 + k];
            bias2[p][hf] = sc * (b_ih[row] + b_hh[row]);
        }
    }

    float hOwn[3] = {0.f, 0.f, 0.f}, hOth[3] = {0.f, 0.f, 0.f}, cS[3] = {0.f, 0.f, 0.f};

    f32x4 acc[8][2];
    #pragma unroll
    for (int m = 0; m < 8; ++m)
        #pragma unroll
        for (int n = 0; n < 2; ++n)
            acc[m][n] = (f32x4){0.f, 0.f, 0.f, 0.f};

    // x: both lanes of a pair load identical addresses (coalescer dedup).
    // One group = 8 timesteps = 48 floats = 12 f32x4.
    const f32x4* xb4 = (const f32x4*)(x + (size_t)(b0 + sloc) * (Tn * In));

    // W1p row base pointers for this lane's two B-fragment rows (L2-resident)
    const unsigned short* wrow[2];
    #pragma unroll
    for (int n = 0; n < 2; ++n) wrow[n] = W1p + (size_t)(wv * 32 + n * 16 + lr) * KP;

    auto LOADB = [&](int g, bf16x8 (&bf)[2][2]) {
        #pragma unroll
        for (int kc = 0; kc < 2; ++kc)
            #pragma unroll
            for (int n = 0; n < 2; ++n)
                bf[kc][n] = *((const bf16x8*)&wrow[n][g * 64 + kc * 32 + lg * 8]);
    };

    auto STEPS8 = [&](const f32x4 (&bx)[12], int slot) {
        #pragma unroll
        for (int s = 0; s < 8; ++s) {
            float xv[6];
            #pragma unroll
            for (int k = 0; k < 6; ++k) { const int fl = s * 6 + k; xv[k] = bx[fl >> 2][fl & 3]; }
            f32x2 a2[6];
            #pragma unroll
            for (int p = 0; p < 6; ++p) a2[p] = bias2[p];
            #pragma unroll
            for (int k = 0; k < 6; ++k) {
                const f32x2 xs = (f32x2){xv[k], xv[k]};
                #pragma unroll
                for (int p = 0; p < 6; ++p) a2[p] = pkfma(Wx[p][k], xs, a2[p]);
            }
            #pragma unroll
            for (int k = 0; k < 3; ++k) {
                const f32x2 hs = (f32x2){hOwn[k], hOwn[k]};
                #pragma unroll
                for (int p = 0; p < 6; ++p) a2[p] = pkfma(Wh[p][k], hs, a2[p]);
            }
            #pragma unroll
            for (int k = 0; k < 3; ++k) {
                const f32x2 hs = (f32x2){hOth[k], hOth[k]};
                #pragma unroll
                for (int p = 0; p < 6; ++p) a2[p] = pkfma(Wh[p][3 + k], hs, a2[p]);
            }
            float av[12];
            #pragma unroll
            for (int p = 0; p < 6; ++p) { av[2 * p] = a2[p][0]; av[2 * p + 1] = a2[p][1]; }

            unsigned short hb[3];
            #pragma unroll
            for (int m = 0; m < 3; ++m) {
                const float iv = rcp1p(av[m]);                       // sigmoid (scale folded)
                const float fv = rcp1p(av[3 + m]);
                const float gv = fmaf(-2.f, rcp1p(av[6 + m]), 1.f);  // tanh (scale folded)
                const float ov = rcp1p(av[9 + m]);
                const float c  = fmaf(fv, cS[m], iv * gv);
                cS[m] = c;
                const float hv = ov * tanh_c(c);
                hOwn[m] = hv;
                hOth[m] = swap1(hv);
                hb[m]   = f2bf(hv);
            }
            u16x4 hw; hw.x = hb[0]; hw.y = hb[1]; hw.z = hb[2]; hw.w = 0;
            *((u16x4*)&htile[slot][s][sloc][role * 4]) = hw;
        }
    };

    auto MFMAG8 = [&](int slot, const bf16x8 (&bf)[2][2]) {
        #pragma unroll
        for (int kc = 0; kc < 2; ++kc) {
            bf16x8 af[8];
            #pragma unroll
            for (int m = 0; m < 8; ++m)
                af[m] = *((const bf16x8*)&htile[slot][kc * 4 + lg][m * 16 + lr][0]);
            #pragma unroll
            for (int n = 0; n < 2; ++n)
                #pragma unroll
                for (int m = 0; m < 8; ++m)
                    acc[m][n] = __builtin_amdgcn_mfma_f32_16x16x32_bf16(af[m], bf[kc][n], acc[m][n], 0, 0, 0);
        }
    };

    f32x4 bufA[12], bufB[12];
    #pragma unroll
    for (int q = 0; q < 12; ++q) bufA[q] = xb4[q];
    bf16x8 bfA[2][2], bfB[2][2];

    for (int gg = 0; gg < 12; ++gg) {      // groups (2gg, 2gg+1); 25th group in tail
        const int gA = 2 * gg, gB = gA + 1;
        #pragma unroll
        for (int q = 0; q < 12; ++q) bufB[q] = xb4[gB * 12 + q];   // prefetch odd group
        LOADB(gA, bfA);
        STEPS8(bufA, 0);
        BAR();
        #pragma unroll
        for (int q = 0; q < 12; ++q) bufA[q] = xb4[(gB + 1) * 12 + q]; // prefetch next even
        MFMAG8(0, bfA);
        LOADB(gB, bfB);
        STEPS8(bufB, 1);
        BAR();
        MFMAG8(1, bfB);
    }
    // tail: group 24 (already in bufA)
    LOADB(24, bfA);
    STEPS8(bufA, 0);
    BAR();
    MFMAG8(0, bfA);

    // ---- epilogue: hid = relu(acc + b1) -> LDS bf16; then out = hid @ W2^T + b2 ----
    float b1v[2];
    #pragma unroll
    for (int n = 0; n < 2; ++n) b1v[n] = b1[wv * 32 + n * 16 + lr];
    #pragma unroll
    for (int m = 0; m < 8; ++m)
        #pragma unroll
        for (int n = 0; n < 2; ++n)
            #pragma unroll
            for (int r = 0; r < 4; ++r)
                hidS[m * 16 + lg * 4 + r][wv * 32 + n * 16 + lr] =
                    f2bf(fmaxf(acc[m][n][r] + b1v[n], 0.f));
    for (int q = tid; q < OUTn * FFn; q += 256) W2s[q] = W2[q];
    __syncthreads();

    const int s2 = tid >> 1;
    const int half = tid & 1;   // 6 outputs each
    float oa[6];
    #pragma unroll
    for (int jj = 0; jj < 6; ++jj) oa[jj] = b2[half * 6 + jj];
    for (int k8 = 0; k8 < 16; ++k8) {
        const u16x8 hv8 = *((const u16x8*)&hidS[s2][k8 * 8]);
        #pragma unroll
        for (int e = 0; e < 8; ++e) {
            const float hv = __uint_as_float(((unsigned)(unsigned short)hv8[e]) << 16);
            const int k = k8 * 8 + e;
            #pragma unroll
            for (int jj = 0; jj < 6; ++jj)
                oa[jj] = fmaf(hv, W2s[(half * 6 + jj) * FFn + k], oa[jj]);
        }
    }
    float* op = out + (size_t)(b0 + s2) * OUTn + half * 6;
    #pragma unroll
    for (int jj = 0; jj < 6; ++jj) op[jj] = oa[jj];
}

extern "C" void kernel_launch(void* const* d_in, const int* in_sizes, int n_in,
                              void* d_out, int out_size, void* d_ws, size_t ws_size,
                              hipStream_t stream) {
    const float* x    = (const float*)d_in[0];
    const float* W_ih = (const float*)d_in[1];
    const float* W_hh = (const float*)d_in[2];
    const float* b_ih = (const float*)d_in[3];
    const float* b_hh = (const float*)d_in[4];
    const float* W1   = (const float*)d_in[5];
    const float* b1   = (const float*)d_in[6];
    const float* W2   = (const float*)d_in[7];
    const float* b2   = (const float*)d_in[8];
    unsigned short* W1p = (unsigned short*)d_ws;   // 128*1600*2B = 400 KB
    float* out = (float*)d_out;

    prep_kernel<<<(FFn * KP + 255) / 256, 256, 0, stream>>>(W1, W1p);
    fused_kernel<<<Bn / 128, 256, 0, stream>>>(x, W_ih, W_hh, b_ih, b_hh,
                                               W1p, b1, W2, b2, out);
}